// Round 7
// baseline (20512.085 us; speedup 1.0000x reference)
//
#include <hip/hip_runtime.h>

#define BB 512
#define TT 128
#define EE 512
#define HH 256
#define VV 39
#define H3 768
#define H2 512
#define TM1 127
#define NEGF (-3.402823466e38f)
#define NBLK 256

typedef unsigned short u16;
typedef unsigned int u32;
typedef __attribute__((ext_vector_type(8))) short s16x8;
typedef __attribute__((ext_vector_type(4))) float f32x4;

__device__ __forceinline__ float b2f(u16 u){ u32 x=((u32)u)<<16; return __uint_as_float(x); }
__device__ __forceinline__ u16 f2b(float f){ u32 x=__float_as_uint(f); u32 r=(x+0x7fffu+((x>>16)&1u))>>16; return (u16)r; }
__device__ __forceinline__ float sigm(float x){ return 1.f/(1.f+__expf(-x)); }
__device__ __forceinline__ float tanh1(float x){ float t=__expf(2.f*x); return 1.f-2.f/(t+1.f); }
__device__ __forceinline__ float bfl(u32 u){ return __uint_as_float(u<<16); }
__device__ __forceinline__ float bfh(u32 u){ return __uint_as_float(u & 0xffff0000u); }

#define MFMA __builtin_amdgcn_mfma_f32_16x16x32_bf16

// Device-scope grid barrier (round-3-proven): release add, relaxed spin, acquire fence.
__device__ __forceinline__ void gbar(u32* cnt, u32 tgt){
  __syncthreads();
  if (threadIdx.x==0){
    __hip_atomic_fetch_add(cnt, 1u, __ATOMIC_RELEASE, __HIP_MEMORY_SCOPE_AGENT);
    while (__hip_atomic_load(cnt, __ATOMIC_RELAXED, __HIP_MEMORY_SCOPE_AGENT) < tgt)
      __builtin_amdgcn_s_sleep(8);
    __threadfence();
  }
  __syncthreads();
}

// ---------------------------------------------------------------------------
// Per-token input-projection tables (V=39).
__global__ __launch_bounds__(256) void k_tables(
    const float* __restrict__ src_emb, const float* __restrict__ trg_emb,
    const float* __restrict__ Wih_f, const float* __restrict__ bih_f,
    const float* __restrict__ Wih_b, const float* __restrict__ bih_b,
    const float* __restrict__ dec_Wih, const float* __restrict__ dec_bih,
    const float* __restrict__ pre_W,
    float* __restrict__ tab_gi_f, float* __restrict__ tab_gi_b,
    float* __restrict__ tab_dec, float* __restrict__ tab_pre)
{
  int v = blockIdx.x;
  int y = blockIdx.y;
  int tid = threadIdx.x;
  if (y < 9){
    int seg = y/3, part = y%3;
    int n = part*256 + tid;
    const float* emb; const float* W; const float* bias; float* out; int ldw;
    if (seg==0){ emb=src_emb; W=Wih_f; bias=bih_f; out=tab_gi_f; ldw=EE; }
    else if (seg==1){ emb=src_emb; W=Wih_b; bias=bih_b; out=tab_gi_b; ldw=EE; }
    else { emb=trg_emb; W=dec_Wih; bias=dec_bih; out=tab_dec; ldw=EE+H2; }
    float acc = bias[n];
    const float* er = emb + (size_t)v*EE;
    const float* wr = W + (size_t)n*ldw;
    for (int k=0;k<EE;k++) acc += er[k]*wr[k];
    out[(size_t)v*H3 + n] = acc;
  } else {
    int n = tid;
    float acc = 0.f;
    const float* er = trg_emb + (size_t)v*EE;
    const float* wr = pre_W + (size_t)n*1280;
    for (int k=0;k<EE;k++) acc += er[k]*wr[k];
    tab_pre[(size_t)v*HH + n] = acc;
  }
}

// All fp32->bf16 weight conversions. grid(5440).
__global__ __launch_bounds__(256) void k_cvt_all(
    const float* __restrict__ eWhh_f, const float* __restrict__ eWhh_b,
    const float* __restrict__ dWhh, const float* __restrict__ dWih,
    const float* __restrict__ Wk, const float* __restrict__ Wq,
    const float* __restrict__ preW, const float* __restrict__ genW,
    u16* __restrict__ o1, u16* __restrict__ o2, u16* __restrict__ o3,
    u16* __restrict__ o4, u16* __restrict__ o5, u16* __restrict__ o6,
    u16* __restrict__ o7, u16* __restrict__ o8, u16* __restrict__ o9)
{
  int idx = blockIdx.x*256 + threadIdx.x;
  const float* src; u16* dst; int cols, ld, off, rel;
  if      (idx <  196608){ rel=idx;          src=eWhh_f; dst=o1; cols=256; ld=256;  off=0;   }
  else if (idx <  393216){ rel=idx-196608;   src=eWhh_b; dst=o2; cols=256; ld=256;  off=0;   }
  else if (idx <  589824){ rel=idx-393216;   src=dWhh;   dst=o3; cols=256; ld=256;  off=0;   }
  else if (idx <  983040){ rel=idx-589824;   src=dWih;   dst=o4; cols=512; ld=1024; off=512; }
  else if (idx < 1114112){ rel=idx-983040;   src=Wk;     dst=o5; cols=512; ld=512;  off=0;   }
  else if (idx < 1179648){ rel=idx-1114112;  src=Wq;     dst=o6; cols=256; ld=256;  off=0;   }
  else if (idx < 1245184){ rel=idx-1179648;  src=preW;   dst=o7; cols=256; ld=1280; off=512; }
  else if (idx < 1376256){ rel=idx-1245184;  src=preW;   dst=o8; cols=512; ld=1280; off=768; }
  else if (idx < 1392640){
    rel=idx-1376256; int r=rel>>8, c2=rel&255;
    o9[rel] = (r<VV)? f2b(genW[(size_t)r*HH + c2]) : (u16)0;
    return;
  }
  else return;
  int r = rel/cols, c2 = rel - r*cols;
  dst[rel] = f2b(src[(size_t)r*ld + off + c2]);
}

// ---------------------------------------------------------------------------
// WHOLE encoder in one kernel, zero grid barriers. grid(32), block 512.
__global__ __launch_bounds__(512) void k_enc_all(const int* __restrict__ input,
    const u16* __restrict__ wb_f, const u16* __restrict__ wb_b,
    const float* __restrict__ bhh_f, const float* __restrict__ bhh_b,
    const float* __restrict__ tab_f, const float* __restrict__ tab_b,
    float* __restrict__ h_f, float* __restrict__ h_b, u16* __restrict__ enc_out)
{
  __shared__ float gh[32][772];
  __shared__ u16 hs[32][264];
  int bx = blockIdx.x;
  int dirb = bx>>4, mt = bx&15;
  int m0 = mt*32;
  int tid = threadIdx.x;
  const float* tab = dirb? tab_b : tab_f;
  const float* bhh = dirb? bhh_b : bhh_f;
  const u16* Wb = dirb? wb_b : wb_f;
  int c = tid & 255, rh = tid>>8;
  float b_r=bhh[c], b_z=bhh[c+256], b_n=bhh[c+512];
  float hreg[16];
  #pragma unroll
  for (int r=0;r<16;r++) hreg[r]=0.f;
  int wv = tid>>6, lane = tid&63, l15 = lane&15, kg=(lane>>4)*8;
  int n0w = wv*96;
  float* hOut = dirb? h_b : h_f;

  for (int s=1; s<=TT; s++){
    int tcol = dirb? (TT-s) : (s-1);
    #pragma unroll
    for (int r=0;r<16;r++){
      int row = rh*16 + r;
      int b = m0 + row;
      int tok = input[b*TT + tcol];
      const float* tg = tab + (size_t)tok*H3;
      float g0=0.f, g1=0.f, g2=0.f;
      if (s>1){ g0=gh[row][c]; g1=gh[row][c+256]; g2=gh[row][c+512]; }
      float rg = sigm(tg[c]     + g0 + b_r);
      float zg = sigm(tg[c+256] + g1 + b_z);
      float ng = tanh1(tg[c+512] + rg*(g2 + b_n));
      float hv = (1.f-zg)*ng + zg*hreg[r];
      hreg[r] = hv;
      u16 hb = f2b(hv);
      hs[row][c] = hb;
      enc_out[((size_t)b*TT + tcol)*H2 + (size_t)dirb*HH + c] = hb;
    }
    if (s==TT){
      #pragma unroll
      for (int r=0;r<16;r++)
        hOut[(size_t)(m0+rh*16+r)*HH + c] = hreg[r];
      break;
    }
    __syncthreads();
    f32x4 acc[2][6];
    #pragma unroll
    for (int rt=0;rt<2;rt++)
      #pragma unroll
      for (int nt=0;nt<6;nt++) acc[rt][nt]=(f32x4){0.f,0.f,0.f,0.f};
    const u16* ar0 = &hs[l15][0];
    const u16* ar1 = &hs[16+l15][0];
    for (int ko=0;ko<256;ko+=32){
      s16x8 a0 = *(const s16x8*)(ar0 + ko + kg);
      s16x8 a1 = *(const s16x8*)(ar1 + ko + kg);
      #pragma unroll
      for (int nt=0;nt<6;nt++){
        s16x8 bf = *(const s16x8*)(Wb + (size_t)(n0w+nt*16+l15)*HH + ko + kg);
        acc[0][nt] = MFMA(a0, bf, acc[0][nt], 0,0,0);
        acc[1][nt] = MFMA(a1, bf, acc[1][nt], 0,0,0);
      }
    }
    int q4 = (lane>>4)*4;
    #pragma unroll
    for (int rt=0;rt<2;rt++)
      #pragma unroll
      for (int nt=0;nt<6;nt++){
        int col = n0w + nt*16 + l15;
        #pragma unroll
        for (int j=0;j<4;j++)
          gh[rt*16 + q4 + j][col] = acc[rt][nt][j];
      }
    __syncthreads();
  }
}

// proj_key = enc_out @ Wk^T : MFMA. grid(1024), block 256.
__global__ __launch_bounds__(256) void k_pk(const u16* __restrict__ enc_out,
    const u16* __restrict__ wbk, u16* __restrict__ pk)
{
  int m0 = blockIdx.x*64;
  int tid = threadIdx.x, wv = tid>>6, lane = tid&63;
  int l15 = lane&15, kg = (lane>>4)*8;
  int n0 = wv*64;
  f32x4 acc[4][4];
  #pragma unroll
  for (int rt=0;rt<4;rt++)
    #pragma unroll
    for (int nt=0;nt<4;nt++) acc[rt][nt] = (f32x4){0.f,0.f,0.f,0.f};
  for (int ko=0; ko<512; ko+=32){
    s16x8 a[4], b[4];
    #pragma unroll
    for (int rt=0;rt<4;rt++) a[rt] = *(const s16x8*)(enc_out + (size_t)(m0+rt*16+l15)*H2 + ko + kg);
    #pragma unroll
    for (int nt=0;nt<4;nt++) b[nt] = *(const s16x8*)(wbk + (size_t)(n0+nt*16+l15)*H2 + ko + kg);
    #pragma unroll
    for (int rt=0;rt<4;rt++)
      #pragma unroll
      for (int nt=0;nt<4;nt++)
        acc[rt][nt] = MFMA(a[rt], b[nt], acc[rt][nt], 0,0,0);
  }
  #pragma unroll
  for (int rt=0;rt<4;rt++){
    int rbase = m0 + rt*16 + (lane>>4)*4;
    #pragma unroll
    for (int nt=0;nt<4;nt++){
      int col = n0 + nt*16 + l15;
      #pragma unroll
      for (int j=0;j<4;j++)
        pk[(size_t)(rbase+j)*HH + col] = f2b(acc[rt][nt][j]);
    }
  }
}

// hidden = tanh([h_f|h_b] @ bridge_W^T + b) -> hst. grid (4,8).
__global__ __launch_bounds__(256) void k_bridge(const float* __restrict__ h_f,
    const float* __restrict__ h_b, const float* __restrict__ bw,
    const float* __restrict__ bb, float* __restrict__ hst)
{
  __shared__ float As[32][68];
  __shared__ float Ws[32][68];
  int n0=blockIdx.x*64, m0=blockIdx.y*64, tid=threadIdx.x;
  int ar=tid>>2, ak=(tid&3)*8;
  int rt=tid>>4, ct=tid&15;
  float acc[4][4];
  #pragma unroll
  for (int j=0;j<4;j++){
    #pragma unroll
    for (int l=0;l<4;l++) acc[j][l]=0.f;
  }
  for (int ko=0;ko<512;ko+=32){
    int k0=ko+ak;
    const float* asrc = (k0<256)? (h_f + (size_t)(m0+ar)*HH + k0)
                                : (h_b + (size_t)(m0+ar)*HH + (k0-256));
    float4 a0=*(const float4*)asrc, a1=*(const float4*)(asrc+4);
    const float* wsrc = bw + (size_t)(n0+ar)*H2 + k0;
    float4 w0=*(const float4*)wsrc, w1=*(const float4*)(wsrc+4);
    __syncthreads();
    As[ak+0][ar]=a0.x; As[ak+1][ar]=a0.y; As[ak+2][ar]=a0.z; As[ak+3][ar]=a0.w;
    As[ak+4][ar]=a1.x; As[ak+5][ar]=a1.y; As[ak+6][ar]=a1.z; As[ak+7][ar]=a1.w;
    Ws[ak+0][ar]=w0.x; Ws[ak+1][ar]=w0.y; Ws[ak+2][ar]=w0.z; Ws[ak+3][ar]=w0.w;
    Ws[ak+4][ar]=w1.x; Ws[ak+5][ar]=w1.y; Ws[ak+6][ar]=w1.z; Ws[ak+7][ar]=w1.w;
    __syncthreads();
    #pragma unroll
    for (int kk=0;kk<32;kk++){
      float4 a=*(const float4*)&As[kk][rt*4];
      float4 w=*(const float4*)&Ws[kk][ct*4];
      float a4[4]={a.x,a.y,a.z,a.w};
      float w4[4]={w.x,w.y,w.z,w.w};
      #pragma unroll
      for (int j=0;j<4;j++){
        #pragma unroll
        for (int l=0;l<4;l++) acc[j][l]+=a4[j]*w4[l];
      }
    }
  }
  #pragma unroll
  for (int j=0;j<4;j++){
    int row=m0+rt*4+j;
    #pragma unroll
    for (int l=0;l<4;l++){
      int col=n0+ct*4+l;
      hst[(size_t)row*HH+col]=tanh1(acc[j][l]+bb[col]);
    }
  }
}

// Bootstrap: q0 = h0@Wq, gh0 = h0@Whh. grid(32), block 256.
__global__ __launch_bounds__(256) void k_boot(
    const float* __restrict__ hst, const u16* __restrict__ whh,
    const u16* __restrict__ wq, float* __restrict__ ghg,
    float* __restrict__ qg)
{
  __shared__ u16 hsb[16][264];
  int bx=blockIdx.x, tid=threadIdx.x;
  int wv=tid>>6, lane=tid&63, l15=lane&15, kg=(lane>>4)*8;
  int b0=bx*16;
  {
    int c=tid;
    for (int r=0;r<16;r++) hsb[r][c] = f2b(hst[(size_t)(b0+r)*HH + c]);
  }
  __syncthreads();
  int rr = (lane>>4)*4;
  for (int nt=0;nt<12;nt++){
    int n0 = wv*192 + nt*16;
    f32x4 acc = (f32x4){0.f,0.f,0.f,0.f};
    for (int ko=0;ko<256;ko+=32){
      s16x8 a = *(const s16x8*)&hsb[l15][ko+kg];
      s16x8 bf = *(const s16x8*)(whh + (size_t)(n0+l15)*HH + ko + kg);
      acc = MFMA(a, bf, acc, 0,0,0);
    }
    #pragma unroll
    for (int jr=0;jr<4;jr++)
      ghg[(size_t)(b0+rr+jr)*H3 + n0 + l15] = acc[jr];
  }
  #pragma unroll
  for (int nt=0;nt<4;nt++){
    int n0 = wv*64 + nt*16;
    f32x4 acc = (f32x4){0.f,0.f,0.f,0.f};
    for (int ko=0;ko<256;ko+=32){
      s16x8 a = *(const s16x8*)&hsb[l15][ko+kg];
      s16x8 bf = *(const s16x8*)(wq + (size_t)(n0+l15)*HH + ko + kg);
      acc = MFMA(a, bf, acc, 0,0,0);
    }
    #pragma unroll
    for (int jr=0;jr<4;jr++)
      qg[(size_t)(b0+rr+jr)*HH + n0 + l15] = acc[jr];
  }
}

// ---------------------------------------------------------------------------
// PERSISTENT decoder. grid(256) x 512 thr, 1 block/CU (LDS 148KB) => co-resident.
// Every block: attention for rows {2bx, 2bx+1}; pk in LDS, enc in VGPRs
// (blocks 0..31 stream instead; their LDS region holds the GEMM scratch).
// Blocks 0..31: 16-row MFMA GEMM chain per step. 2 grid barriers/step.
__global__ __launch_bounds__(512,2) void k_dec_p(
    const int* __restrict__ input,
    const float* __restrict__ tab_dec, const float* __restrict__ tab_pre,
    const float* __restrict__ bhh, const float* __restrict__ We,
    const u16* __restrict__ whh, const u16* __restrict__ wih,
    const u16* __restrict__ wq, const u16* __restrict__ wph,
    const u16* __restrict__ wpc, const u16* __restrict__ wgen,
    const u16* __restrict__ pk, const u16* __restrict__ enc_out,
    float* __restrict__ hst, float* __restrict__ qg, float* __restrict__ ghg,
    u16* __restrict__ ctx_bf, float* __restrict__ nll_part,
    float* __restrict__ outp, u32* __restrict__ bar)
{
  __shared__ __align__(16) char smem[151552];
  u16* pkL = (u16*)smem;                                  // [2][128][256] resident
  float* qS = (float*)(smem+131072);                      // [512]
  float* aL = (float*)(smem+133120);                      // [2][128]
  int* stok = (int*)(smem+134144);                        // [2][128]
  float (*part)[512] = (float(*)[512])(smem+135168);      // [8][512]
  // gemm aliases (blocks 0..31 only; region 0..58432)
  u16 (*cs)[520]  = (u16(*)[520])smem;
  u16 (*hsb)[264] = (u16(*)[264])(smem+16640);
  u16 (*gicL)[776]= (u16(*)[776])(smem+25088);
  u16 (*preb)[264]= (u16(*)[264])(smem+25088);            // aliases gicL (after gates)
  float (*lgt)[64]= (float(*)[64])(smem+33536);           // aliases gicL tail
  u16 (*pcL)[264] = (u16(*)[264])(smem+49920);
  int* stokL      = (int*)(smem+58368);

  int bx=blockIdx.x, tid=threadIdx.x;
  int wv=tid>>6, lane=tid&63, l15=lane&15, kg=(lane>>4)*8;
  int rsel = wv>>2, wl = wv&3;
  int rowA = bx*2;
  int isg = (bx<32);
  int b0 = bx*16;
  uint4 encr[32];
  float4 weL = *(const float4*)(We + lane*4);
  float b_r, b_z, b_n;
  { int c=tid&255; b_r=bhh[c]; b_z=bhh[c+256]; b_n=bhh[c+512]; }
  if (tid<256) stok[tid] = input[(rowA + (tid>>7))*TT + (tid&127)];
  if (!isg){
    const u16* pkb = pk + (size_t)rowA*TT*HH;
    for (int e=tid*8; e<2*TT*HH; e+=512*8)
      *(uint4*)(pkL+e) = *(const uint4*)(pkb+e);
    const u16* eb = enc_out + ((size_t)(rowA+rsel)*TT + wl*32)*H2 + lane*8;
    #pragma unroll
    for (int tt=0;tt<32;tt++) encr[tt] = *(const uint4*)(eb + (size_t)tt*H2);
  }
  float nlacc = 0.f;
  __syncthreads();
  u32 phase = 0;

  for (int j=0;j<TM1;j++){
    // ---- load q for both rows
    qS[tid] = qg[(size_t)(rowA + (tid>>8))*HH + (tid&255)];
    __syncthreads();
    // ---- e[t] = We . tanh(q + pk[t]); wave wv: row rsel, t in [wl*32,+32)
    {
      float4 qq = *(const float4*)&qS[rsel*256 + lane*4];
      if (!isg){
        const u16* pr = pkL + rsel*TT*HH + lane*4;
        for (int tt=0;tt<32;tt++){
          int t = wl*32+tt;
          uint2 pp = *(const uint2*)(pr + t*HH);
          float s = tanh1(qq.x+bfl(pp.x))*weL.x + tanh1(qq.y+bfh(pp.x))*weL.y
                  + tanh1(qq.z+bfl(pp.y))*weL.z + tanh1(qq.w+bfh(pp.y))*weL.w;
          #pragma unroll
          for (int off=32; off; off>>=1) s += __shfl_xor(s,off);
          if (lane==0) aL[rsel*128+t] = stok[rsel*128+t] ? s : NEGF;
        }
      } else {
        const u16* pr = pk + (size_t)(rowA+rsel)*TT*HH + lane*4;
        for (int tt=0;tt<32;tt++){
          int t = wl*32+tt;
          uint2 pp = *(const uint2*)(pr + (size_t)t*HH);
          float s = tanh1(qq.x+bfl(pp.x))*weL.x + tanh1(qq.y+bfh(pp.x))*weL.y
                  + tanh1(qq.z+bfl(pp.y))*weL.z + tanh1(qq.w+bfh(pp.y))*weL.w;
          #pragma unroll
          for (int off=32; off; off>>=1) s += __shfl_xor(s,off);
          if (lane==0) aL[rsel*128+t] = stok[rsel*128+t] ? s : NEGF;
        }
      }
    }
    __syncthreads();
    if (wl==0){   // waves 0,4: softmax for row rsel
      float v0 = aL[rsel*128+lane], v1 = aL[rsel*128+64+lane];
      float m = fmaxf(v0,v1);
      #pragma unroll
      for (int off=32; off; off>>=1) m = fmaxf(m, __shfl_xor(m,off));
      float p0 = __expf(v0-m), p1 = __expf(v1-m);
      float s = p0+p1;
      #pragma unroll
      for (int off=32; off; off>>=1) s += __shfl_xor(s,off);
      float inv = 1.f/s;
      aL[rsel*128+lane] = p0*inv; aL[rsel*128+64+lane] = p1*inv;
    }
    __syncthreads();
    // ---- ctx partials: wave wv: its 32 t, lane dims [8lane,+8)
    {
      float cacc[8];
      #pragma unroll
      for (int e2=0;e2<8;e2++) cacc[e2]=0.f;
      if (!isg){
        #pragma unroll
        for (int tt=0;tt<32;tt++){
          float a = aL[rsel*128 + wl*32 + tt];
          uint4 ev = encr[tt];
          cacc[0]+=a*bfl(ev.x); cacc[1]+=a*bfh(ev.x);
          cacc[2]+=a*bfl(ev.y); cacc[3]+=a*bfh(ev.y);
          cacc[4]+=a*bfl(ev.z); cacc[5]+=a*bfh(ev.z);
          cacc[6]+=a*bfl(ev.w); cacc[7]+=a*bfh(ev.w);
        }
      } else {
        const u16* eb = enc_out + ((size_t)(rowA+rsel)*TT + wl*32)*H2 + lane*8;
        for (int tt=0;tt<32;tt++){
          uint4 ev = *(const uint4*)(eb + (size_t)tt*H2);
          float a = aL[rsel*128 + wl*32 + tt];
          cacc[0]+=a*bfl(ev.x); cacc[1]+=a*bfh(ev.x);
          cacc[2]+=a*bfl(ev.y); cacc[3]+=a*bfh(ev.y);
          cacc[4]+=a*bfl(ev.z); cacc[5]+=a*bfh(ev.z);
          cacc[6]+=a*bfl(ev.w); cacc[7]+=a*bfh(ev.w);
        }
      }
      *(float4*)&part[wv][lane*8]   = (float4){cacc[0],cacc[1],cacc[2],cacc[3]};
      *(float4*)&part[wv][lane*8+4] = (float4){cacc[4],cacc[5],cacc[6],cacc[7]};
    }
    __syncthreads();
    {
      int rs = tid>>8, d = tid&255;
      int base = rs*4;
      float c0 = part[base][d]+part[base+1][d]+part[base+2][d]+part[base+3][d];
      float c1 = part[base][d+256]+part[base+1][d+256]+part[base+2][d+256]+part[base+3][d+256];
      u16* cb = ctx_bf + (size_t)(rowA+rs)*H2;
      cb[d] = f2b(c0); cb[d+256] = f2b(c1);
    }
    gbar(bar, (++phase)*NBLK);

    // ---- GEMM chain (blocks 0..31)
    if (isg){
      for (int idx=tid; idx<16*64; idx+=512){
        int r=idx>>6, cc=(idx&63)*8;
        *(uint4*)&cs[r][cc] = *(const uint4*)(ctx_bf + (size_t)(b0+r)*H2 + cc);
      }
      if (tid<16) stokL[tid] = input[(b0+tid)*TT + j];
      __syncthreads();
      int rr = (lane>>4)*4;
      // gic = ctx @ Wih_ctx^T (N=768, K=512): 6 ntiles/wave
      #pragma unroll 2
      for (int nt=0;nt<6;nt++){
        int n0 = wv*96 + nt*16;
        f32x4 acc = (f32x4){0.f,0.f,0.f,0.f};
        for (int ko=0;ko<512;ko+=32){
          s16x8 a = *(const s16x8*)&cs[l15][ko+kg];
          s16x8 bf = *(const s16x8*)(wih + (size_t)(n0+l15)*H2 + ko + kg);
          acc = MFMA(a,bf,acc,0,0,0);
        }
        #pragma unroll
        for (int jr=0;jr<4;jr++) gicL[rr+jr][n0+l15] = f2b(acc[jr]);
      }
      // pc = ctx @ wpre_ctx^T (N=256): 2 ntiles/wave
      #pragma unroll
      for (int nt=0;nt<2;nt++){
        int n0 = wv*32 + nt*16;
        f32x4 acc = (f32x4){0.f,0.f,0.f,0.f};
        for (int ko=0;ko<512;ko+=32){
          s16x8 a = *(const s16x8*)&cs[l15][ko+kg];
          s16x8 bf = *(const s16x8*)(wpc + (size_t)(n0+l15)*H2 + ko + kg);
          acc = MFMA(a,bf,acc,0,0,0);
        }
        #pragma unroll
        for (int jr=0;jr<4;jr++) pcL[rr+jr][n0+l15] = f2b(acc[jr]);
      }
      __syncthreads();
      // gates -> h_{j+1}: c=tid&255, rows (tid>>8)*8..+8
      {
        int c = tid&255, rh = tid>>8;
        for (int r=rh*8; r<rh*8+8; r++){
          int bb = b0+r;
          const float* tg = tab_dec + (size_t)stokL[r]*H3;
          const float* gr = ghg + (size_t)bb*H3;
          float rg = sigm(tg[c]     + b2f(gicL[r][c])     + gr[c]     + b_r);
          float zg = sigm(tg[c+256] + b2f(gicL[r][c+256]) + gr[c+256] + b_z);
          float ng = tanh1(tg[c+512] + b2f(gicL[r][c+512]) + rg*(gr[c+512] + b_n));
          float hv = (1.f-zg)*ng + zg*hst[(size_t)bb*HH + c];
          hst[(size_t)bb*HH + c] = hv;
          hsb[r][c] = f2b(hv);
        }
      }
      __syncthreads();
      // gh_{j+1} = h @ Whh^T (N=768)
      #pragma unroll 2
      for (int nt=0;nt<6;nt++){
        int n0 = wv*96 + nt*16;
        f32x4 acc = (f32x4){0.f,0.f,0.f,0.f};
        for (int ko=0;ko<256;ko+=32){
          s16x8 a = *(const s16x8*)&hsb[l15][ko+kg];
          s16x8 bf = *(const s16x8*)(whh + (size_t)(n0+l15)*HH + ko + kg);
          acc = MFMA(a,bf,acc,0,0,0);
        }
        #pragma unroll
        for (int jr=0;jr<4;jr++)
          ghg[(size_t)(b0+rr+jr)*H3 + n0 + l15] = acc[jr];
      }
      // q_{j+1} = h @ Wq^T (N=256)
      #pragma unroll
      for (int nt=0;nt<2;nt++){
        int n0 = wv*32 + nt*16;
        f32x4 acc = (f32x4){0.f,0.f,0.f,0.f};
        for (int ko=0;ko<256;ko+=32){
          s16x8 a = *(const s16x8*)&hsb[l15][ko+kg];
          s16x8 bf = *(const s16x8*)(wq + (size_t)(n0+l15)*HH + ko + kg);
          acc = MFMA(a,bf,acc,0,0,0);
        }
        #pragma unroll
        for (int jr=0;jr<4;jr++)
          qg[(size_t)(b0+rr+jr)*HH + n0 + l15] = acc[jr];
      }
      // pre = tab_pre + pc + h @ wpre_h^T (N=256)
      #pragma unroll
      for (int nt=0;nt<2;nt++){
        int n0 = wv*32 + nt*16;
        f32x4 acc = (f32x4){0.f,0.f,0.f,0.f};
        for (int ko=0;ko<256;ko+=32){
          s16x8 a = *(const s16x8*)&hsb[l15][ko+kg];
          s16x8 bf = *(const s16x8*)(wph + (size_t)(n0+l15)*HH + ko + kg);
          acc = MFMA(a,bf,acc,0,0,0);
        }
        #pragma unroll
        for (int jr=0;jr<4;jr++){
          int r = rr+jr;
          float pv = acc[jr] + b2f(pcL[r][n0+l15]) + tab_pre[(size_t)stokL[r]*HH + n0 + l15];
          preb[r][n0+l15] = f2b(pv);
        }
      }
      __syncthreads();
      // logits = pre @ genW^T (N=64): waves 0..3
      if (wv<4){
        int n0 = wv*16;
        f32x4 acc = (f32x4){0.f,0.f,0.f,0.f};
        for (int ko=0;ko<256;ko+=32){
          s16x8 a = *(const s16x8*)&preb[l15][ko+kg];
          s16x8 bf = *(const s16x8*)(wgen + (size_t)(n0+l15)*HH + ko + kg);
          acc = MFMA(a,bf,acc,0,0,0);
        }
        #pragma unroll
        for (int jr=0;jr<4;jr++) lgt[rr+jr][n0+l15] = acc[jr];
      }
      __syncthreads();
      // nll: 16-lane group per row
      {
        int r = wv*4 + (lane>>4);
        if (r < 16){
          float v0 = lgt[r][l15];
          float v1 = lgt[r][l15+16];
          float v2 = (l15<7)? lgt[r][l15+32] : NEGF;
          float m = fmaxf(fmaxf(v0,v1),v2);
          #pragma unroll
          for (int off=8; off; off>>=1) m = fmaxf(m, __shfl_xor(m,off));
          float pe = __expf(v0-m) + __expf(v1-m) + ((l15<7)? __expf(v2-m) : 0.f);
          #pragma unroll
          for (int off=8; off; off>>=1) pe += __shfl_xor(pe,off);
          if (l15==0){
            int ty = input[(b0+r)*TT + j+1];
            if (ty != 0) nlacc += m + __logf(pe) - lgt[r][ty];
          }
        }
      }
    }
    gbar(bar, (++phase)*NBLK);
  }

  if (isg){
    int r = wv*4 + (lane>>4);
    if (r<16 && l15==0) nll_part[b0+r] = nlacc;
  }
  gbar(bar, (++phase)*NBLK);
  if (bx==0){
    float* red = (float*)part;
    red[tid] = nll_part[tid];
    __syncthreads();
    for (int off=256; off; off>>=1){
      if (tid<off) red[tid] += red[tid+off];
      __syncthreads();
    }
    if (tid==0) outp[0] = red[0];
  }
}

extern "C" void kernel_launch(void* const* d_in, const int* in_sizes, int n_in,
                              void* d_out, int out_size, void* d_ws, size_t ws_size,
                              hipStream_t stream)
{
  const int*   input    = (const int*)  d_in[0];
  const float* src_emb  = (const float*)d_in[1];
  const float* trg_emb  = (const float*)d_in[2];
  const float* eWih_f   = (const float*)d_in[3];
  const float* eWhh_f   = (const float*)d_in[4];
  const float* ebih_f   = (const float*)d_in[5];
  const float* ebhh_f   = (const float*)d_in[6];
  const float* eWih_b   = (const float*)d_in[7];
  const float* eWhh_b   = (const float*)d_in[8];
  const float* ebih_b   = (const float*)d_in[9];
  const float* ebhh_b   = (const float*)d_in[10];
  const float* bridge_W = (const float*)d_in[11];
  const float* bridge_b = (const float*)d_in[12];
  const float* attn_Wk  = (const float*)d_in[13];
  const float* attn_Wq  = (const float*)d_in[14];
  const float* attn_We  = (const float*)d_in[15];
  const float* dec_Wih  = (const float*)d_in[16];
  const float* dec_Whh  = (const float*)d_in[17];
  const float* dec_bih  = (const float*)d_in[18];
  const float* dec_bhh  = (const float*)d_in[19];
  const float* pre_W    = (const float*)d_in[20];
  const float* gen_W    = (const float*)d_in[21];

  float* F = (float*)d_ws;
  size_t o=0;
  u32* bar        = (u32*)(F+o); o+=16;
  float* tab_gi_f = F+o; o+=(size_t)VV*H3;
  float* tab_gi_b = F+o; o+=(size_t)VV*H3;
  float* tab_dec  = F+o; o+=(size_t)VV*H3;
  float* tab_pre  = F+o; o+=(size_t)VV*HH;
  float* h_f      = F+o; o+=(size_t)BB*HH;
  float* h_b      = F+o; o+=(size_t)BB*HH;
  float* hst      = F+o; o+=(size_t)BB*HH;
  float* qg       = F+o; o+=(size_t)BB*HH;
  float* ghg      = F+o; o+=(size_t)BB*H3;
  float* nll_part = F+o; o+=(size_t)BB;
  u16* U = (u16*)(F+o);
  size_t uo=0;
  u16* enc_out = U+uo; uo+=(size_t)BB*TT*H2;
  u16* pk      = U+uo; uo+=(size_t)BB*TT*HH;
  u16* ctx_bf  = U+uo; uo+=(size_t)BB*H2;
  u16* wb_ehh_f= U+uo; uo+=(size_t)H3*HH;
  u16* wb_ehh_b= U+uo; uo+=(size_t)H3*HH;
  u16* wb_dhh  = U+uo; uo+=(size_t)H3*HH;
  u16* wb_dih  = U+uo; uo+=(size_t)H3*H2;
  u16* wb_wk   = U+uo; uo+=(size_t)HH*H2;
  u16* wb_wq   = U+uo; uo+=(size_t)HH*HH;
  u16* wb_ph   = U+uo; uo+=(size_t)HH*HH;
  u16* wb_pc   = U+uo; uo+=(size_t)HH*H2;
  u16* wb_gen  = U+uo; uo+=(size_t)64*HH;

  dim3 blk(256,1,1);
  k_tables<<<dim3(VV,10),blk,0,stream>>>(src_emb,trg_emb,eWih_f,ebih_f,eWih_b,ebih_b,
                                         dec_Wih,dec_bih,pre_W,
                                         tab_gi_f,tab_gi_b,tab_dec,tab_pre);
  k_cvt_all<<<dim3(5440),blk,0,stream>>>(eWhh_f,eWhh_b,dec_Whh,dec_Wih,attn_Wk,attn_Wq,pre_W,gen_W,
                                         wb_ehh_f,wb_ehh_b,wb_dhh,wb_dih,wb_wk,wb_wq,
                                         wb_ph,wb_pc,wb_gen);
  k_enc_all<<<dim3(32),dim3(512),0,stream>>>(input,wb_ehh_f,wb_ehh_b,ebhh_f,ebhh_b,
                                             tab_gi_f,tab_gi_b,h_f,h_b,enc_out);
  k_pk<<<dim3(1024),blk,0,stream>>>(enc_out,wb_wk,pk);
  k_bridge<<<dim3(4,8),blk,0,stream>>>(h_f,h_b,bridge_W,bridge_b,hst);
  k_boot<<<dim3(32),blk,0,stream>>>(hst,wb_dhh,wb_wq,ghg,qg);
  hipMemsetAsync(bar, 0, sizeof(u32), stream);
  k_dec_p<<<dim3(NBLK),dim3(512),0,stream>>>(input,tab_dec,tab_pre,dec_bhh,attn_We,
                                             wb_dhh,wb_dih,wb_wq,wb_ph,wb_pc,wb_gen,
                                             pk,enc_out,hst,qg,ghg,ctx_bf,nll_part,
                                             (float*)d_out,bar);
}

// Round 9
// 18349.138 us; speedup vs baseline: 1.1179x; 1.1179x over previous
//
#include <hip/hip_runtime.h>

#define BB 512
#define TT 128
#define EE 512
#define HH 256
#define VV 39
#define H3 768
#define H2 512
#define TM1 127
#define NEGF (-3.402823466e38f)

typedef unsigned short u16;
typedef unsigned int u32;
typedef __attribute__((ext_vector_type(8))) short s16x8;
typedef __attribute__((ext_vector_type(4))) float f32x4;
typedef __attribute__((ext_vector_type(2))) unsigned int u32x2;
typedef __attribute__((ext_vector_type(4))) unsigned int u32x4;

__device__ __forceinline__ float b2f(u16 u){ u32 x=((u32)u)<<16; return __uint_as_float(x); }
__device__ __forceinline__ u16 f2b(float f){ u32 x=__float_as_uint(f); u32 r=(x+0x7fffu+((x>>16)&1u))>>16; return (u16)r; }
__device__ __forceinline__ float sigm(float x){ return 1.f/(1.f+__expf(-x)); }
__device__ __forceinline__ float tanh1(float x){ float t=__expf(2.f*x); return 1.f-2.f/(t+1.f); }
__device__ __forceinline__ float bfl(u32 u){ return __uint_as_float(u<<16); }
__device__ __forceinline__ float bfh(u32 u){ return __uint_as_float(u & 0xffff0000u); }

#define MFMA __builtin_amdgcn_mfma_f32_16x16x32_bf16

// agent-scope coherent u32 ops (go to coherence point; no cache fences needed)
__device__ __forceinline__ u32 aload(const u32* p){
  return __hip_atomic_load(p, __ATOMIC_RELAXED, __HIP_MEMORY_SCOPE_AGENT);
}
__device__ __forceinline__ void astore(u32* p, u32 v){
  __hip_atomic_store(p, v, __ATOMIC_RELAXED, __HIP_MEMORY_SCOPE_AGENT);
}
__device__ __forceinline__ void cfence(){ asm volatile("" ::: "memory"); }

// flag layout in fl[]: QF(g)=g*16 ; CF(g,a)=512+(g*8+a)*16 ; DN=5120
#define QF(g) ((g)*16)
#define CF(g,a) (512 + ((g)*8+(a))*16)
#define DN 5120

// ---------------------------------------------------------------------------
__global__ __launch_bounds__(256) void k_tables(
    const float* __restrict__ src_emb, const float* __restrict__ trg_emb,
    const float* __restrict__ Wih_f, const float* __restrict__ bih_f,
    const float* __restrict__ Wih_b, const float* __restrict__ bih_b,
    const float* __restrict__ dec_Wih, const float* __restrict__ dec_bih,
    const float* __restrict__ pre_W,
    float* __restrict__ tab_gi_f, float* __restrict__ tab_gi_b,
    float* __restrict__ tab_dec, float* __restrict__ tab_pre)
{
  int v = blockIdx.x;
  int y = blockIdx.y;
  int tid = threadIdx.x;
  if (y < 9){
    int seg = y/3, part = y%3;
    int n = part*256 + tid;
    const float* emb; const float* W; const float* bias; float* out; int ldw;
    if (seg==0){ emb=src_emb; W=Wih_f; bias=bih_f; out=tab_gi_f; ldw=EE; }
    else if (seg==1){ emb=src_emb; W=Wih_b; bias=bih_b; out=tab_gi_b; ldw=EE; }
    else { emb=trg_emb; W=dec_Wih; bias=dec_bih; out=tab_dec; ldw=EE+H2; }
    float acc = bias[n];
    const float* er = emb + (size_t)v*EE;
    const float* wr = W + (size_t)n*ldw;
    for (int k=0;k<EE;k++) acc += er[k]*wr[k];
    out[(size_t)v*H3 + n] = acc;
  } else {
    int n = tid;
    float acc = 0.f;
    const float* er = trg_emb + (size_t)v*EE;
    const float* wr = pre_W + (size_t)n*1280;
    for (int k=0;k<EE;k++) acc += er[k]*wr[k];
    tab_pre[(size_t)v*HH + n] = acc;
  }
}

__global__ __launch_bounds__(256) void k_cvt_all(
    const float* __restrict__ eWhh_f, const float* __restrict__ eWhh_b,
    const float* __restrict__ dWhh, const float* __restrict__ dWih,
    const float* __restrict__ Wk, const float* __restrict__ Wq,
    const float* __restrict__ preW, const float* __restrict__ genW,
    u16* __restrict__ o1, u16* __restrict__ o2, u16* __restrict__ o3,
    u16* __restrict__ o4, u16* __restrict__ o5, u16* __restrict__ o6,
    u16* __restrict__ o7, u16* __restrict__ o8, u16* __restrict__ o9)
{
  int idx = blockIdx.x*256 + threadIdx.x;
  const float* src; u16* dst; int cols, ld, off, rel;
  if      (idx <  196608){ rel=idx;          src=eWhh_f; dst=o1; cols=256; ld=256;  off=0;   }
  else if (idx <  393216){ rel=idx-196608;   src=eWhh_b; dst=o2; cols=256; ld=256;  off=0;   }
  else if (idx <  589824){ rel=idx-393216;   src=dWhh;   dst=o3; cols=256; ld=256;  off=0;   }
  else if (idx <  983040){ rel=idx-589824;   src=dWih;   dst=o4; cols=512; ld=1024; off=512; }
  else if (idx < 1114112){ rel=idx-983040;   src=Wk;     dst=o5; cols=512; ld=512;  off=0;   }
  else if (idx < 1179648){ rel=idx-1114112;  src=Wq;     dst=o6; cols=256; ld=256;  off=0;   }
  else if (idx < 1245184){ rel=idx-1179648;  src=preW;   dst=o7; cols=256; ld=1280; off=512; }
  else if (idx < 1376256){ rel=idx-1245184;  src=preW;   dst=o8; cols=512; ld=1280; off=768; }
  else if (idx < 1392640){
    rel=idx-1376256; int r=rel>>8, c2=rel&255;
    o9[rel] = (r<VV)? f2b(genW[(size_t)r*HH + c2]) : (u16)0;
    return;
  }
  else return;
  int r = rel/cols, c2 = rel - r*cols;
  dst[rel] = f2b(src[(size_t)r*ld + off + c2]);
}

// ---------------------------------------------------------------------------
__global__ __launch_bounds__(512) void k_enc_all(const int* __restrict__ input,
    const u16* __restrict__ wb_f, const u16* __restrict__ wb_b,
    const float* __restrict__ bhh_f, const float* __restrict__ bhh_b,
    const float* __restrict__ tab_f, const float* __restrict__ tab_b,
    float* __restrict__ h_f, float* __restrict__ h_b, u16* __restrict__ enc_out)
{
  __shared__ float gh[32][772];
  __shared__ u16 hs[32][264];
  int bx = blockIdx.x;
  int dirb = bx>>4, mt = bx&15;
  int m0 = mt*32;
  int tid = threadIdx.x;
  const float* tab = dirb? tab_b : tab_f;
  const float* bhh = dirb? bhh_b : bhh_f;
  const u16* Wb = dirb? wb_b : wb_f;
  int c = tid & 255, rh = tid>>8;
  float b_r=bhh[c], b_z=bhh[c+256], b_n=bhh[c+512];
  float hreg[16];
  #pragma unroll
  for (int r=0;r<16;r++) hreg[r]=0.f;
  int wv = tid>>6, lane = tid&63, l15 = lane&15, kg=(lane>>4)*8;
  int n0w = wv*96;
  float* hOut = dirb? h_b : h_f;

  for (int s=1; s<=TT; s++){
    int tcol = dirb? (TT-s) : (s-1);
    #pragma unroll
    for (int r=0;r<16;r++){
      int row = rh*16 + r;
      int b = m0 + row;
      int tok = input[b*TT + tcol];
      const float* tg = tab + (size_t)tok*H3;
      float g0=0.f, g1=0.f, g2=0.f;
      if (s>1){ g0=gh[row][c]; g1=gh[row][c+256]; g2=gh[row][c+512]; }
      float rg = sigm(tg[c]     + g0 + b_r);
      float zg = sigm(tg[c+256] + g1 + b_z);
      float ng = tanh1(tg[c+512] + rg*(g2 + b_n));
      float hv = (1.f-zg)*ng + zg*hreg[r];
      hreg[r] = hv;
      u16 hb = f2b(hv);
      hs[row][c] = hb;
      enc_out[((size_t)b*TT + tcol)*H2 + (size_t)dirb*HH + c] = hb;
    }
    if (s==TT){
      #pragma unroll
      for (int r=0;r<16;r++)
        hOut[(size_t)(m0+rh*16+r)*HH + c] = hreg[r];
      break;
    }
    __syncthreads();
    f32x4 acc[2][6];
    #pragma unroll
    for (int rt=0;rt<2;rt++)
      #pragma unroll
      for (int nt=0;nt<6;nt++) acc[rt][nt]=(f32x4){0.f,0.f,0.f,0.f};
    const u16* ar0 = &hs[l15][0];
    const u16* ar1 = &hs[16+l15][0];
    for (int ko=0;ko<256;ko+=32){
      s16x8 a0 = *(const s16x8*)(ar0 + ko + kg);
      s16x8 a1 = *(const s16x8*)(ar1 + ko + kg);
      #pragma unroll
      for (int nt=0;nt<6;nt++){
        s16x8 bf = *(const s16x8*)(Wb + (size_t)(n0w+nt*16+l15)*HH + ko + kg);
        acc[0][nt] = MFMA(a0, bf, acc[0][nt], 0,0,0);
        acc[1][nt] = MFMA(a1, bf, acc[1][nt], 0,0,0);
      }
    }
    int q4 = (lane>>4)*4;
    #pragma unroll
    for (int rt=0;rt<2;rt++)
      #pragma unroll
      for (int nt=0;nt<6;nt++){
        int col = n0w + nt*16 + l15;
        #pragma unroll
        for (int j=0;j<4;j++)
          gh[rt*16 + q4 + j][col] = acc[rt][nt][j];
      }
    __syncthreads();
  }
}

__global__ __launch_bounds__(256) void k_pk(const u16* __restrict__ enc_out,
    const u16* __restrict__ wbk, u16* __restrict__ pk)
{
  int m0 = blockIdx.x*64;
  int tid = threadIdx.x, wv = tid>>6, lane = tid&63;
  int l15 = lane&15, kg = (lane>>4)*8;
  int n0 = wv*64;
  f32x4 acc[4][4];
  #pragma unroll
  for (int rt=0;rt<4;rt++)
    #pragma unroll
    for (int nt=0;nt<4;nt++) acc[rt][nt] = (f32x4){0.f,0.f,0.f,0.f};
  for (int ko=0; ko<512; ko+=32){
    s16x8 a[4], b[4];
    #pragma unroll
    for (int rt=0;rt<4;rt++) a[rt] = *(const s16x8*)(enc_out + (size_t)(m0+rt*16+l15)*H2 + ko + kg);
    #pragma unroll
    for (int nt=0;nt<4;nt++) b[nt] = *(const s16x8*)(wbk + (size_t)(n0+nt*16+l15)*H2 + ko + kg);
    #pragma unroll
    for (int rt=0;rt<4;rt++)
      #pragma unroll
      for (int nt=0;nt<4;nt++)
        acc[rt][nt] = MFMA(a[rt], b[nt], acc[rt][nt], 0,0,0);
  }
  #pragma unroll
  for (int rt=0;rt<4;rt++){
    int rbase = m0 + rt*16 + (lane>>4)*4;
    #pragma unroll
    for (int nt=0;nt<4;nt++){
      int col = n0 + nt*16 + l15;
      #pragma unroll
      for (int j=0;j<4;j++)
        pk[(size_t)(rbase+j)*HH + col] = f2b(acc[rt][nt][j]);
    }
  }
}

__global__ __launch_bounds__(256) void k_bridge(const float* __restrict__ h_f,
    const float* __restrict__ h_b, const float* __restrict__ bw,
    const float* __restrict__ bb, float* __restrict__ hst)
{
  __shared__ float As[32][68];
  __shared__ float Ws[32][68];
  int n0=blockIdx.x*64, m0=blockIdx.y*64, tid=threadIdx.x;
  int ar=tid>>2, ak=(tid&3)*8;
  int rt=tid>>4, ct=tid&15;
  float acc[4][4];
  #pragma unroll
  for (int j=0;j<4;j++){
    #pragma unroll
    for (int l=0;l<4;l++) acc[j][l]=0.f;
  }
  for (int ko=0;ko<512;ko+=32){
    int k0=ko+ak;
    const float* asrc = (k0<256)? (h_f + (size_t)(m0+ar)*HH + k0)
                                : (h_b + (size_t)(m0+ar)*HH + (k0-256));
    float4 a0=*(const float4*)asrc, a1=*(const float4*)(asrc+4);
    const float* wsrc = bw + (size_t)(n0+ar)*H2 + k0;
    float4 w0=*(const float4*)wsrc, w1=*(const float4*)(wsrc+4);
    __syncthreads();
    As[ak+0][ar]=a0.x; As[ak+1][ar]=a0.y; As[ak+2][ar]=a0.z; As[ak+3][ar]=a0.w;
    As[ak+4][ar]=a1.x; As[ak+5][ar]=a1.y; As[ak+6][ar]=a1.z; As[ak+7][ar]=a1.w;
    Ws[ak+0][ar]=w0.x; Ws[ak+1][ar]=w0.y; Ws[ak+2][ar]=w0.z; Ws[ak+3][ar]=w0.w;
    Ws[ak+4][ar]=w1.x; Ws[ak+5][ar]=w1.y; Ws[ak+6][ar]=w1.z; Ws[ak+7][ar]=w1.w;
    __syncthreads();
    #pragma unroll
    for (int kk=0;kk<32;kk++){
      float4 a=*(const float4*)&As[kk][rt*4];
      float4 w=*(const float4*)&Ws[kk][ct*4];
      float a4[4]={a.x,a.y,a.z,a.w};
      float w4[4]={w.x,w.y,w.z,w.w};
      #pragma unroll
      for (int j=0;j<4;j++){
        #pragma unroll
        for (int l=0;l<4;l++) acc[j][l]+=a4[j]*w4[l];
      }
    }
  }
  #pragma unroll
  for (int j=0;j<4;j++){
    int row=m0+rt*4+j;
    #pragma unroll
    for (int l=0;l<4;l++){
      int col=n0+ct*4+l;
      hst[(size_t)row*HH+col]=tanh1(acc[j][l]+bb[col]);
    }
  }
}

__global__ __launch_bounds__(256) void k_boot(
    const float* __restrict__ hst, const u16* __restrict__ whh,
    const u16* __restrict__ wq, float* __restrict__ ghg,
    float* __restrict__ qg)
{
  __shared__ u16 hsb[16][264];
  int bx=blockIdx.x, tid=threadIdx.x;
  int wv=tid>>6, lane=tid&63, l15=lane&15, kg=(lane>>4)*8;
  int b0=bx*16;
  {
    int c=tid;
    for (int r=0;r<16;r++) hsb[r][c] = f2b(hst[(size_t)(b0+r)*HH + c]);
  }
  __syncthreads();
  int rr = (lane>>4)*4;
  for (int nt=0;nt<12;nt++){
    int n0 = wv*192 + nt*16;
    f32x4 acc = (f32x4){0.f,0.f,0.f,0.f};
    for (int ko=0;ko<256;ko+=32){
      s16x8 a = *(const s16x8*)&hsb[l15][ko+kg];
      s16x8 bf = *(const s16x8*)(whh + (size_t)(n0+l15)*HH + ko + kg);
      acc = MFMA(a, bf, acc, 0,0,0);
    }
    #pragma unroll
    for (int jr=0;jr<4;jr++)
      ghg[(size_t)(b0+rr+jr)*H3 + n0 + l15] = acc[jr];
  }
  #pragma unroll
  for (int nt=0;nt<4;nt++){
    int n0 = wv*64 + nt*16;
    f32x4 acc = (f32x4){0.f,0.f,0.f,0.f};
    for (int ko=0;ko<256;ko+=32){
      s16x8 a = *(const s16x8*)&hsb[l15][ko+kg];
      s16x8 bf = *(const s16x8*)(wq + (size_t)(n0+l15)*HH + ko + kg);
      acc = MFMA(a, bf, acc, 0,0,0);
    }
    #pragma unroll
    for (int jr=0;jr<4;jr++)
      qg[(size_t)(b0+rr+jr)*HH + n0 + l15] = acc[jr];
  }
}

// ---------------------------------------------------------------------------
// PERSISTENT decoder, flag-based producer-consumer sync (no barriers/fences).
// grid(256) x 512. All blocks: attention for rows {2bx,2bx+1} (pk LDS-resident,
// enc VGPR-resident; blocks<32 stream nontemporally — LDS holds GEMM scratch).
// Blocks 0..31: per-step 16-row MFMA GEMM chain; weights stay L2-resident.
__global__ __launch_bounds__(512,2) void k_dec_p(
    const int* __restrict__ input,
    const float* __restrict__ tab_dec, const float* __restrict__ tab_pre,
    const float* __restrict__ bhh, const float* __restrict__ We,
    const u16* __restrict__ whh, const u16* __restrict__ wih,
    const u16* __restrict__ wq, const u16* __restrict__ wph,
    const u16* __restrict__ wpc, const u16* __restrict__ wgen,
    const u16* __restrict__ pk, const u16* __restrict__ enc_out,
    float* __restrict__ hst, u32* __restrict__ qgu, float* __restrict__ ghg,
    u32* __restrict__ ctxu, u32* __restrict__ nllu,
    float* __restrict__ outp, u32* __restrict__ fl)
{
  __shared__ __align__(16) char smem[151552];
  u16* pkL = (u16*)smem;                                  // [2][128][256] resident
  float* qS = (float*)(smem+131072);                      // [512]
  float* aL = (float*)(smem+133120);                      // [2][128]
  int* stok = (int*)(smem+134144);                        // [2][128]
  float (*part)[512] = (float(*)[512])(smem+135168);      // [8][512]
  // gemm aliases (blocks 0..31 only)
  u16 (*cs)[520]  = (u16(*)[520])smem;
  u16 (*hsb)[264] = (u16(*)[264])(smem+16640);
  u16 (*gicL)[776]= (u16(*)[776])(smem+25088);
  u16 (*preb)[264]= (u16(*)[264])(smem+25088);
  float (*lgt)[64]= (float(*)[64])(smem+33536);
  u16 (*pcL)[264] = (u16(*)[264])(smem+49920);
  int* stokL      = (int*)(smem+58368);

  int bx=blockIdx.x, tid=threadIdx.x;
  int wv=tid>>6, lane=tid&63, l15=lane&15, kg=(lane>>4)*8;
  int rsel = wv>>2, wl = wv&3;
  int rowA = bx*2;
  int g = bx>>3;                 // gemm-owner of this block's attn rows
  int isg = (bx<32);
  int b0 = bx*16;
  u32x4 encr[32];
  float4 weL = *(const float4*)(We + lane*4);
  float b_r, b_z, b_n;
  { int c=tid&255; b_r=bhh[c]; b_z=bhh[c+256]; b_n=bhh[c+512]; }
  if (tid<256) stok[tid] = input[(rowA + (tid>>7))*TT + (tid&127)];
  if (!isg){
    const u16* pkb = pk + (size_t)rowA*TT*HH;
    for (int e=tid*8; e<2*TT*HH; e+=512*8)
      *(u32x4*)(pkL+e) = *(const u32x4*)(pkb+e);
    const u16* eb = enc_out + ((size_t)(rowA+rsel)*TT + wl*32)*H2 + lane*8;
    #pragma unroll
    for (int tt=0;tt<32;tt++) encr[tt] = *(const u32x4*)(eb + (size_t)tt*H2);
  }
  float nlacc = 0.f;
  __syncthreads();

  for (int j=0;j<TM1;j++){
    // ======== attention phase for step j (all blocks, 2 rows) ========
    if (j>0){
      if (tid==0){
        while (aload(&fl[QF(g)]) < (u32)j) __builtin_amdgcn_s_sleep(1);
      }
      __syncthreads();
      cfence();
    }
    qS[tid] = __uint_as_float(aload(qgu + (size_t)rowA*HH + tid));
    __syncthreads();
    {
      float4 qq = *(const float4*)&qS[rsel*256 + lane*4];
      if (!isg){
        const u16* pr = pkL + rsel*TT*HH + lane*4;
        for (int tt=0;tt<32;tt++){
          int t = wl*32+tt;
          u32x2 pp = *(const u32x2*)(pr + t*HH);
          float s = tanh1(qq.x+bfl(pp.x))*weL.x + tanh1(qq.y+bfh(pp.x))*weL.y
                  + tanh1(qq.z+bfl(pp.y))*weL.z + tanh1(qq.w+bfh(pp.y))*weL.w;
          #pragma unroll
          for (int off=32; off; off>>=1) s += __shfl_xor(s,off);
          if (lane==0) aL[rsel*128+t] = stok[rsel*128+t] ? s : NEGF;
        }
      } else {
        const u16* pr = pk + (size_t)(rowA+rsel)*TT*HH + lane*4;
        for (int tt=0;tt<32;tt++){
          int t = wl*32+tt;
          u32x2 pp = __builtin_nontemporal_load((const u32x2*)(pr + (size_t)t*HH));
          float s = tanh1(qq.x+bfl(pp.x))*weL.x + tanh1(qq.y+bfh(pp.x))*weL.y
                  + tanh1(qq.z+bfl(pp.y))*weL.z + tanh1(qq.w+bfh(pp.y))*weL.w;
          #pragma unroll
          for (int off=32; off; off>>=1) s += __shfl_xor(s,off);
          if (lane==0) aL[rsel*128+t] = stok[rsel*128+t] ? s : NEGF;
        }
      }
    }
    __syncthreads();
    if (wl==0){
      float v0 = aL[rsel*128+lane], v1 = aL[rsel*128+64+lane];
      float m = fmaxf(v0,v1);
      #pragma unroll
      for (int off=32; off; off>>=1) m = fmaxf(m, __shfl_xor(m,off));
      float p0 = __expf(v0-m), p1 = __expf(v1-m);
      float s = p0+p1;
      #pragma unroll
      for (int off=32; off; off>>=1) s += __shfl_xor(s,off);
      float inv = 1.f/s;
      aL[rsel*128+lane] = p0*inv; aL[rsel*128+64+lane] = p1*inv;
    }
    __syncthreads();
    {
      float cacc[8];
      #pragma unroll
      for (int e2=0;e2<8;e2++) cacc[e2]=0.f;
      if (!isg){
        #pragma unroll
        for (int tt=0;tt<32;tt++){
          float a = aL[rsel*128 + wl*32 + tt];
          u32x4 ev = encr[tt];
          cacc[0]+=a*bfl(ev.x); cacc[1]+=a*bfh(ev.x);
          cacc[2]+=a*bfl(ev.y); cacc[3]+=a*bfh(ev.y);
          cacc[4]+=a*bfl(ev.z); cacc[5]+=a*bfh(ev.z);
          cacc[6]+=a*bfl(ev.w); cacc[7]+=a*bfh(ev.w);
        }
      } else {
        const u16* eb = enc_out + ((size_t)(rowA+rsel)*TT + wl*32)*H2 + lane*8;
        for (int tt=0;tt<32;tt++){
          u32x4 ev = __builtin_nontemporal_load((const u32x4*)(eb + (size_t)tt*H2));
          float a = aL[rsel*128 + wl*32 + tt];
          cacc[0]+=a*bfl(ev.x); cacc[1]+=a*bfh(ev.x);
          cacc[2]+=a*bfl(ev.y); cacc[3]+=a*bfh(ev.y);
          cacc[4]+=a*bfl(ev.z); cacc[5]+=a*bfh(ev.z);
          cacc[6]+=a*bfl(ev.w); cacc[7]+=a*bfh(ev.w);
        }
      }
      *(float4*)&part[wv][lane*8]   = (float4){cacc[0],cacc[1],cacc[2],cacc[3]};
      *(float4*)&part[wv][lane*8+4] = (float4){cacc[4],cacc[5],cacc[6],cacc[7]};
    }
    __syncthreads();
    {
      int k = tid&255, rs = tid>>8, base = rs*4;
      float c0 = part[base][2*k]  +part[base+1][2*k]  +part[base+2][2*k]  +part[base+3][2*k];
      float c1 = part[base][2*k+1]+part[base+1][2*k+1]+part[base+2][2*k+1]+part[base+3][2*k+1];
      u32 w = (u32)f2b(c0) | ((u32)f2b(c1)<<16);
      astore(ctxu + (size_t)(rowA+rs)*256 + k, w);
    }
    __syncthreads();   // drains ctx stores (vmcnt) for all waves
    if (tid==0)
      __hip_atomic_store(&fl[CF(g, bx&7)], (u32)(j+1), __ATOMIC_RELEASE, __HIP_MEMORY_SCOPE_AGENT);

    // ======== gemm phase for step j (blocks 0..31, 16 rows) ========
    if (isg){
      if (tid<8){
        while (aload(&fl[CF(bx,tid)]) < (u32)(j+1)) __builtin_amdgcn_s_sleep(1);
      }
      __syncthreads();
      cfence();
      for (int idx=tid; idx<4096; idx+=512){
        int r = idx>>8, k = idx&255;
        u32 w = aload(ctxu + (size_t)(b0+r)*256 + k);
        *(u32*)&cs[r][2*k] = w;
      }
      if (tid<16) stokL[tid] = input[(b0+tid)*TT + j];
      __syncthreads();
      int rr = (lane>>4)*4;
      // gic = ctx @ Wih_ctx^T (N=768, K=512)
      #pragma unroll 2
      for (int nt=0;nt<6;nt++){
        int n0 = wv*96 + nt*16;
        f32x4 acc = (f32x4){0.f,0.f,0.f,0.f};
        for (int ko=0;ko<512;ko+=32){
          s16x8 a = *(const s16x8*)&cs[l15][ko+kg];
          s16x8 bf = *(const s16x8*)(wih + (size_t)(n0+l15)*H2 + ko + kg);
          acc = MFMA(a,bf,acc,0,0,0);
        }
        #pragma unroll
        for (int jr=0;jr<4;jr++) gicL[rr+jr][n0+l15] = f2b(acc[jr]);
      }
      // pc = ctx @ wpre_ctx^T (N=256)
      #pragma unroll
      for (int nt=0;nt<2;nt++){
        int n0 = wv*32 + nt*16;
        f32x4 acc = (f32x4){0.f,0.f,0.f,0.f};
        for (int ko=0;ko<512;ko+=32){
          s16x8 a = *(const s16x8*)&cs[l15][ko+kg];
          s16x8 bf = *(const s16x8*)(wpc + (size_t)(n0+l15)*H2 + ko + kg);
          acc = MFMA(a,bf,acc,0,0,0);
        }
        #pragma unroll
        for (int jr=0;jr<4;jr++) pcL[rr+jr][n0+l15] = f2b(acc[jr]);
      }
      __syncthreads();
      // gates -> h_{j+1}
      {
        int c = tid&255, rh = tid>>8;
        for (int r=rh*8; r<rh*8+8; r++){
          int bb = b0+r;
          const float* tg = tab_dec + (size_t)stokL[r]*H3;
          const float* gr = ghg + (size_t)bb*H3;
          float rg = sigm(tg[c]     + b2f(gicL[r][c])     + gr[c]     + b_r);
          float zg = sigm(tg[c+256] + b2f(gicL[r][c+256]) + gr[c+256] + b_z);
          float ng = tanh1(tg[c+512] + b2f(gicL[r][c+512]) + rg*(gr[c+512] + b_n));
          float hv = (1.f-zg)*ng + zg*hst[(size_t)bb*HH + c];
          hst[(size_t)bb*HH + c] = hv;
          hsb[r][c] = f2b(hv);
        }
      }
      __syncthreads();
      // q_{j+1} = h @ Wq^T FIRST, then publish flag (unblocks attention)
      #pragma unroll
      for (int nt=0;nt<2;nt++){
        int n0 = wv*32 + nt*16;
        f32x4 acc = (f32x4){0.f,0.f,0.f,0.f};
        for (int ko=0;ko<256;ko+=32){
          s16x8 a = *(const s16x8*)&hsb[l15][ko+kg];
          s16x8 bf = *(const s16x8*)(wq + (size_t)(n0+l15)*HH + ko + kg);
          acc = MFMA(a,bf,acc,0,0,0);
        }
        #pragma unroll
        for (int jr=0;jr<4;jr++)
          astore(qgu + (size_t)(b0+rr+jr)*HH + n0 + l15, __float_as_uint(acc[jr]));
      }
      __syncthreads();   // drain q stores
      if (tid==0)
        __hip_atomic_store(&fl[QF(bx)], (u32)(j+1), __ATOMIC_RELEASE, __HIP_MEMORY_SCOPE_AGENT);
      // gh_{j+1} = h @ Whh^T (N=768) — private, plain stores
      #pragma unroll 2
      for (int nt=0;nt<6;nt++){
        int n0 = wv*96 + nt*16;
        f32x4 acc = (f32x4){0.f,0.f,0.f,0.f};
        for (int ko=0;ko<256;ko+=32){
          s16x8 a = *(const s16x8*)&hsb[l15][ko+kg];
          s16x8 bf = *(const s16x8*)(whh + (size_t)(n0+l15)*HH + ko + kg);
          acc = MFMA(a,bf,acc,0,0,0);
        }
        #pragma unroll
        for (int jr=0;jr<4;jr++)
          ghg[(size_t)(b0+rr+jr)*H3 + n0 + l15] = acc[jr];
      }
      // pre = tab_pre + pc + h @ wpre_h^T (N=256)
      #pragma unroll
      for (int nt=0;nt<2;nt++){
        int n0 = wv*32 + nt*16;
        f32x4 acc = (f32x4){0.f,0.f,0.f,0.f};
        for (int ko=0;ko<256;ko+=32){
          s16x8 a = *(const s16x8*)&hsb[l15][ko+kg];
          s16x8 bf = *(const s16x8*)(wph + (size_t)(n0+l15)*HH + ko + kg);
          acc = MFMA(a,bf,acc,0,0,0);
        }
        #pragma unroll
        for (int jr=0;jr<4;jr++){
          int r = rr+jr;
          float pv = acc[jr] + b2f(pcL[r][n0+l15]) + tab_pre[(size_t)stokL[r]*HH + n0 + l15];
          preb[r][n0+l15] = f2b(pv);
        }
      }
      __syncthreads();
      // logits = pre @ genW^T (N=64): waves 0..3
      if (wv<4){
        int n0 = wv*16;
        f32x4 acc = (f32x4){0.f,0.f,0.f,0.f};
        for (int ko=0;ko<256;ko+=32){
          s16x8 a = *(const s16x8*)&preb[l15][ko+kg];
          s16x8 bf = *(const s16x8*)(wgen + (size_t)(n0+l15)*HH + ko + kg);
          acc = MFMA(a,bf,acc,0,0,0);
        }
        #pragma unroll
        for (int jr=0;jr<4;jr++) lgt[rr+jr][n0+l15] = acc[jr];
      }
      __syncthreads();
      {
        int r = wv*4 + (lane>>4);
        if (r < 16){
          float v0 = lgt[r][l15];
          float v1 = lgt[r][l15+16];
          float v2 = (l15<7)? lgt[r][l15+32] : NEGF;
          float m = fmaxf(fmaxf(v0,v1),v2);
          #pragma unroll
          for (int off=8; off; off>>=1) m = fmaxf(m, __shfl_xor(m,off));
          float pe = __expf(v0-m) + __expf(v1-m) + ((l15<7)? __expf(v2-m) : 0.f);
          #pragma unroll
          for (int off=8; off; off>>=1) pe += __shfl_xor(pe,off);
          if (l15==0){
            int ty = input[(b0+r)*TT + j+1];
            if (ty != 0) nlacc += m + __logf(pe) - lgt[r][ty];
          }
        }
      }
      __syncthreads();
    }
  }

  // ---- epilogue: nll gather + reduce
  if (isg){
    int r = wv*4 + (lane>>4);
    if (r<16 && l15==0) astore(nllu + b0 + r, __float_as_uint(nlacc));
    __syncthreads();   // drain
    if (tid==0)
      __hip_atomic_fetch_add(&fl[DN], 1u, __ATOMIC_RELEASE, __HIP_MEMORY_SCOPE_AGENT);
  }
  if (bx==0){
    if (tid==0){
      while (aload(&fl[DN]) < 32u) __builtin_amdgcn_s_sleep(2);
    }
    __syncthreads();
    cfence();
    float* red = (float*)part;
    red[tid] = __uint_as_float(aload(nllu + tid));
    __syncthreads();
    for (int off=256; off; off>>=1){
      if (tid<off) red[tid] += red[tid+off];
      __syncthreads();
    }
    if (tid==0) outp[0] = red[0];
  }
}

extern "C" void kernel_launch(void* const* d_in, const int* in_sizes, int n_in,
                              void* d_out, int out_size, void* d_ws, size_t ws_size,
                              hipStream_t stream)
{
  const int*   input    = (const int*)  d_in[0];
  const float* src_emb  = (const float*)d_in[1];
  const float* trg_emb  = (const float*)d_in[2];
  const float* eWih_f   = (const float*)d_in[3];
  const float* eWhh_f   = (const float*)d_in[4];
  const float* ebih_f   = (const float*)d_in[5];
  const float* ebhh_f   = (const float*)d_in[6];
  const float* eWih_b   = (const float*)d_in[7];
  const float* eWhh_b   = (const float*)d_in[8];
  const float* ebih_b   = (const float*)d_in[9];
  const float* ebhh_b   = (const float*)d_in[10];
  const float* bridge_W = (const float*)d_in[11];
  const float* bridge_b = (const float*)d_in[12];
  const float* attn_Wk  = (const float*)d_in[13];
  const float* attn_Wq  = (const float*)d_in[14];
  const float* attn_We  = (const float*)d_in[15];
  const float* dec_Wih  = (const float*)d_in[16];
  const float* dec_Whh  = (const float*)d_in[17];
  const float* dec_bih  = (const float*)d_in[18];
  const float* dec_bhh  = (const float*)d_in[19];
  const float* pre_W    = (const float*)d_in[20];
  const float* gen_W    = (const float*)d_in[21];

  float* F = (float*)d_ws;
  size_t o=0;
  u32* fl         = (u32*)(F+o); o+=8192;          // flags (memset below)
  float* tab_gi_f = F+o; o+=(size_t)VV*H3;
  float* tab_gi_b = F+o; o+=(size_t)VV*H3;
  float* tab_dec  = F+o; o+=(size_t)VV*H3;
  float* tab_pre  = F+o; o+=(size_t)VV*HH;
  float* h_f      = F+o; o+=(size_t)BB*HH;
  float* h_b      = F+o; o+=(size_t)BB*HH;
  float* hst      = F+o; o+=(size_t)BB*HH;
  float* qg       = F+o; o+=(size_t)BB*HH;
  float* ghg      = F+o; o+=(size_t)BB*H3;
  float* nllb     = F+o; o+=(size_t)BB;
  u16* U = (u16*)(F+o);
  size_t uo=0;
  u16* enc_out = U+uo; uo+=(size_t)BB*TT*H2;
  u16* pk      = U+uo; uo+=(size_t)BB*TT*HH;
  u16* ctx_bf  = U+uo; uo+=(size_t)BB*H2;
  u16* wb_ehh_f= U+uo; uo+=(size_t)H3*HH;
  u16* wb_ehh_b= U+uo; uo+=(size_t)H3*HH;
  u16* wb_dhh  = U+uo; uo+=(size_t)H3*HH;
  u16* wb_dih  = U+uo; uo+=(size_t)H3*H2;
  u16* wb_wk   = U+uo; uo+=(size_t)HH*H2;
  u16* wb_wq   = U+uo; uo+=(size_t)HH*HH;
  u16* wb_ph   = U+uo; uo+=(size_t)HH*HH;
  u16* wb_pc   = U+uo; uo+=(size_t)HH*H2;
  u16* wb_gen  = U+uo; uo+=(size_t)64*HH;

  dim3 blk(256,1,1);
  k_tables<<<dim3(VV,10),blk,0,stream>>>(src_emb,trg_emb,eWih_f,ebih_f,eWih_b,ebih_b,
                                         dec_Wih,dec_bih,pre_W,
                                         tab_gi_f,tab_gi_b,tab_dec,tab_pre);
  k_cvt_all<<<dim3(5440),blk,0,stream>>>(eWhh_f,eWhh_b,dec_Whh,dec_Wih,attn_Wk,attn_Wq,pre_W,gen_W,
                                         wb_ehh_f,wb_ehh_b,wb_dhh,wb_dih,wb_wk,wb_wq,
                                         wb_ph,wb_pc,wb_gen);
  k_enc_all<<<dim3(32),dim3(512),0,stream>>>(input,wb_ehh_f,wb_ehh_b,ebhh_f,ebhh_b,
                                             tab_gi_f,tab_gi_b,h_f,h_b,enc_out);
  k_pk<<<dim3(1024),blk,0,stream>>>(enc_out,wb_wk,pk);
  k_bridge<<<dim3(4,8),blk,0,stream>>>(h_f,h_b,bridge_W,bridge_b,hst);
  k_boot<<<dim3(32),blk,0,stream>>>(hst,wb_dhh,wb_wq,ghg,qg);
  hipMemsetAsync(fl, 0, 32768, stream);
  k_dec_p<<<dim3(256),dim3(512),0,stream>>>(input,tab_dec,tab_pre,dec_bhh,attn_We,
                                            wb_dhh,wb_dih,wb_wq,wb_ph,wb_pc,wb_gen,
                                            pk,enc_out,hst,(u32*)qg,ghg,
                                            (u32*)ctx_bf,(u32*)nllb,
                                            (float*)d_out,fl);
}